// Round 3
// baseline (683.259 us; speedup 1.0000x reference)
//
#include <hip/hip_runtime.h>
#include <hip/hip_bf16.h>

#define N_NODES 8192
#define NF      256
#define L2E     1.44269504088896341f

typedef __attribute__((ext_vector_type(8))) short short8;
typedef __attribute__((ext_vector_type(4))) short short4v;
typedef __attribute__((ext_vector_type(4))) float floatx4;

static __device__ __forceinline__ float bf2f(short s) {
    return __uint_as_float(((unsigned)(unsigned short)s) << 16);
}
static __device__ __forceinline__ short f2bf_rn(float f) {
    unsigned u = __float_as_uint(f) + 0x8000u;
    return (short)(u >> 16);
}
// split fp32 -> bf16 hi + bf16 lo (x ~= hi + lo, |err| ~ 2^-18 |x|)
struct bfpair { short hi, lo; };
static __device__ __forceinline__ bfpair split_bf(float x) {
    bfpair p;
    p.hi = f2bf_rn(x);
    p.lo = f2bf_rn(x - bf2f(p.hi));
    return p;
}

// ---------------------------------------------------------------------------
// K1: WhT[n][i] = sum_k X[i][k] * W[n][k]  (fp32 in via hi/lo bf16 MFMA, fp32 acc)
// Also emits per-(nb)-partial s_src/s_dst from the fp32 accumulators.
// grid 512 = 128 i-tiles(64) x 4 n-tiles(64); 4 waves; no LDS.
// ---------------------------------------------------------------------------
__global__ __launch_bounds__(256) void k1_gemm(const float* __restrict__ X,
                                               const float* __restrict__ W,
                                               const float* __restrict__ r,
                                               short* __restrict__ WhT,
                                               float* __restrict__ sp_src,
                                               float* __restrict__ sp_dst) {
    const int ib = blockIdx.x >> 2;
    const int nb = blockIdx.x & 3;
    const int wave = threadIdx.x >> 6, lane = threadIdx.x & 63;
    const int q = lane >> 4, m = lane & 15;
    const int irow = ib * 64 + wave * 16 + m;

    floatx4 acc[4] = {};
    const float* xp = X + (size_t)irow * NF;
    #pragma unroll
    for (int ks = 0; ks < 8; ++ks) {
        const float* xq = xp + ks * 32 + q * 8;
        float4 xa = *(const float4*)(xq);
        float4 xb = *(const float4*)(xq + 4);
        const float xs[8] = {xa.x, xa.y, xa.z, xa.w, xb.x, xb.y, xb.z, xb.w};
        short8 xh, xl;
        #pragma unroll
        for (int c = 0; c < 8; ++c) {
            bfpair p = split_bf(xs[c]);
            xh[c] = p.hi; xl[c] = p.lo;
        }
        #pragma unroll
        for (int ct = 0; ct < 4; ++ct) {
            const int n = nb * 64 + ct * 16 + m;
            const float* wp = W + (size_t)n * NF + ks * 32 + q * 8;
            float4 wa = *(const float4*)(wp);
            float4 wb = *(const float4*)(wp + 4);
            const float wsv[8] = {wa.x, wa.y, wa.z, wa.w, wb.x, wb.y, wb.z, wb.w};
            short8 wh, wl;
            #pragma unroll
            for (int c = 0; c < 8; ++c) {
                bfpair p = split_bf(wsv[c]);
                wh[c] = p.hi; wl[c] = p.lo;
            }
            acc[ct] = __builtin_amdgcn_mfma_f32_16x16x32_bf16(xh, wh, acc[ct], 0, 0, 0);
            acc[ct] = __builtin_amdgcn_mfma_f32_16x16x32_bf16(xh, wl, acc[ct], 0, 0, 0);
            acc[ct] = __builtin_amdgcn_mfma_f32_16x16x32_bf16(xl, wh, acc[ct], 0, 0, 0);
        }
    }

    // C/D layout: col = lane&15 (n), row = q*4 + reg (i)
    const int i0 = ib * 64 + wave * 16 + q * 4;
    float vs[4] = {0.f, 0.f, 0.f, 0.f}, vd[4] = {0.f, 0.f, 0.f, 0.f};
    #pragma unroll
    for (int ct = 0; ct < 4; ++ct) {
        const int n = nb * 64 + ct * 16 + m;
        short4v v;
        #pragma unroll
        for (int r2 = 0; r2 < 4; ++r2) v[r2] = f2bf_rn(acc[ct][r2]);
        *(short4v*)(WhT + (size_t)n * N_NODES + i0) = v;
        const float rs = r[n], rd = r[NF + n];
        #pragma unroll
        for (int r2 = 0; r2 < 4; ++r2) {
            vs[r2] = fmaf(acc[ct][r2], rs, vs[r2]);
            vd[r2] = fmaf(acc[ct][r2], rd, vd[r2]);
        }
    }
    // reduce over the 16 m-lanes (bits 0..3 of lane)
    #pragma unroll
    for (int mask = 1; mask <= 8; mask <<= 1) {
        #pragma unroll
        for (int r2 = 0; r2 < 4; ++r2) {
            vs[r2] += __shfl_xor(vs[r2], mask);
            vd[r2] += __shfl_xor(vd[r2], mask);
        }
    }
    if (m == 0) {
        #pragma unroll
        for (int r2 = 0; r2 < 4; ++r2) {
            sp_src[nb * N_NODES + i0 + r2] = vs[r2];
            sp_dst[nb * N_NODES + i0 + r2] = vd[r2];
        }
    }
}

// ---------------------------------------------------------------------------
// K2: sum the 4 n-block partials -> s_src/s_dst; per-block max of s_dst -> pmax
// ---------------------------------------------------------------------------
__global__ __launch_bounds__(256) void k2_sv(const float* __restrict__ sp_src,
                                             const float* __restrict__ sp_dst,
                                             float* __restrict__ s_src,
                                             float* __restrict__ s_dst,
                                             float* __restrict__ pmax) {
    __shared__ float red[256];
    const int tid = threadIdx.x;
    const int i = blockIdx.x * 256 + tid;
    float ss = 0.f, sd = 0.f;
    #pragma unroll
    for (int nb = 0; nb < 4; ++nb) {
        ss += sp_src[nb * N_NODES + i];
        sd += sp_dst[nb * N_NODES + i];
    }
    s_src[i] = ss;
    s_dst[i] = sd;
    red[tid] = sd;
    __syncthreads();
    for (int off = 128; off > 0; off >>= 1) {
        if (tid < off) red[tid] = fmaxf(red[tid], red[tid + off]);
        __syncthreads();
    }
    if (tid == 0) pmax[blockIdx.x] = red[0];
}

// ---------------------------------------------------------------------------
// K4: fused masked-softmax attention + PV matmul + exact GELU (fp32 out).
// grid 256 x 512 thr (8 waves): wave&1 -> 16-row half, wave>>1 -> 64-col group.
// P computed directly in MFMA-A register layout; no LDS/barriers in K-loop.
// ---------------------------------------------------------------------------
static __device__ __forceinline__ void pgroup(const int4 a, const floatx4 t,
                                              const float s_i, const float d_i,
                                              float* p) {
    const int av[4] = {a.x, a.y, a.z, a.w};
    #pragma unroll
    for (int c = 0; c < 4; ++c) {
        float sum = s_i + t[c];
        float lr  = fmaxf(sum, 0.2f * sum);                      // leaky-relu
        float pp  = __builtin_amdgcn_exp2f(fmaf(lr, L2E, d_i));  // exp(lr - c_i)
        p[c] = (av[c] != 0) ? pp : 0.0f;
    }
}

__global__ __launch_bounds__(512, 2) void k4_attn(const int* __restrict__ Adj,
                                                  const short* __restrict__ WhT,
                                                  const float* __restrict__ s_dst,
                                                  const float* __restrict__ s_src,
                                                  const float* __restrict__ pmax,
                                                  float* __restrict__ out) {
    const int tid = threadIdx.x;
    const int wave = tid >> 6, lane = tid & 63;
    const int q = lane >> 4, m = lane & 15;
    const int rowhalf = wave & 1, cg = wave >> 1;
    const int i0 = blockIdx.x * 32 + rowhalf * 16;
    const int row = i0 + m;
    const int n0 = cg * 64;

    float M = pmax[0];
    #pragma unroll
    for (int b = 1; b < 32; ++b) M = fmaxf(M, pmax[b]);
    const float s_i = s_src[row];
    const float e0 = s_i + M;
    const float d_i = -fmaxf(e0, 0.2f * e0) * L2E;   // -c_i*log2(e); c_i >= row max

    const int jq = q * 8;
    const int* __restrict__ Arow = Adj + (size_t)row * N_NODES;
    const short* __restrict__ bb0 = WhT + (size_t)(n0 +  0 + m) * N_NODES + jq;
    const short* __restrict__ bb1 = WhT + (size_t)(n0 + 16 + m) * N_NODES + jq;
    const short* __restrict__ bb2 = WhT + (size_t)(n0 + 32 + m) * N_NODES + jq;
    const short* __restrict__ bb3 = WhT + (size_t)(n0 + 48 + m) * N_NODES + jq;

    floatx4 acc0 = {}, acc1 = {}, acc2 = {}, acc3 = {};
    float den = 0.f;

    int4 a0 = *(const int4*)(Arow + jq);
    int4 a1 = *(const int4*)(Arow + jq + 4);
    int4 a2 = *(const int4*)(Arow + jq + 32);
    int4 a3 = *(const int4*)(Arow + jq + 36);
    floatx4 t0 = *(const floatx4*)(s_dst + jq);
    floatx4 t1 = *(const floatx4*)(s_dst + jq + 4);
    floatx4 t2 = *(const floatx4*)(s_dst + jq + 32);
    floatx4 t3 = *(const floatx4*)(s_dst + jq + 36);

    for (int jt = 0; jt < 128; ++jt) {
        const int jb = jt * 64;
        short8 b00 = *(const short8*)(bb0 + jb);
        short8 b01 = *(const short8*)(bb0 + jb + 32);
        short8 b10 = *(const short8*)(bb1 + jb);
        short8 b11 = *(const short8*)(bb1 + jb + 32);
        short8 b20 = *(const short8*)(bb2 + jb);
        short8 b21 = *(const short8*)(bb2 + jb + 32);
        short8 b30 = *(const short8*)(bb3 + jb);
        short8 b31 = *(const short8*)(bb3 + jb + 32);

        const int jn = (jt < 127) ? jb + 64 : jb;
        int4 na0 = *(const int4*)(Arow + jn + jq);
        int4 na1 = *(const int4*)(Arow + jn + jq + 4);
        int4 na2 = *(const int4*)(Arow + jn + jq + 32);
        int4 na3 = *(const int4*)(Arow + jn + jq + 36);
        floatx4 nt0 = *(const floatx4*)(s_dst + jn + jq);
        floatx4 nt1 = *(const floatx4*)(s_dst + jn + jq + 4);
        floatx4 nt2 = *(const floatx4*)(s_dst + jn + jq + 32);
        floatx4 nt3 = *(const floatx4*)(s_dst + jn + jq + 36);

        float p[16];
        pgroup(a0, t0, s_i, d_i, p);
        pgroup(a1, t1, s_i, d_i, p + 4);
        pgroup(a2, t2, s_i, d_i, p + 8);
        pgroup(a3, t3, s_i, d_i, p + 12);

        short8 af0, af1;
        #pragma unroll
        for (int c = 0; c < 8; ++c) { af0[c] = f2bf_rn(p[c]); af1[c] = f2bf_rn(p[8 + c]); }
        float ds = 0.f;
        #pragma unroll
        for (int c = 0; c < 16; ++c) ds += p[c];
        den += ds;

        acc0 = __builtin_amdgcn_mfma_f32_16x16x32_bf16(af0, b00, acc0, 0, 0, 0);
        acc0 = __builtin_amdgcn_mfma_f32_16x16x32_bf16(af1, b01, acc0, 0, 0, 0);
        acc1 = __builtin_amdgcn_mfma_f32_16x16x32_bf16(af0, b10, acc1, 0, 0, 0);
        acc1 = __builtin_amdgcn_mfma_f32_16x16x32_bf16(af1, b11, acc1, 0, 0, 0);
        acc2 = __builtin_amdgcn_mfma_f32_16x16x32_bf16(af0, b20, acc2, 0, 0, 0);
        acc2 = __builtin_amdgcn_mfma_f32_16x16x32_bf16(af1, b21, acc2, 0, 0, 0);
        acc3 = __builtin_amdgcn_mfma_f32_16x16x32_bf16(af0, b30, acc3, 0, 0, 0);
        acc3 = __builtin_amdgcn_mfma_f32_16x16x32_bf16(af1, b31, acc3, 0, 0, 0);

        a0 = na0; a1 = na1; a2 = na2; a3 = na3;
        t0 = nt0; t1 = nt1; t2 = nt2; t3 = nt3;
    }

    // full row denominator (reduce over the q bits), then fan out to C/D rows
    den += __shfl_xor(den, 16);
    den += __shfl_xor(den, 32);
    float invd[4];
    #pragma unroll
    for (int r2 = 0; r2 < 4; ++r2)
        invd[r2] = 1.0f / fmaxf(__shfl(den, q * 4 + r2), 1e-30f);

    floatx4 accs[4] = {acc0, acc1, acc2, acc3};
    #pragma unroll
    for (int ct = 0; ct < 4; ++ct) {
        const int n = n0 + ct * 16 + m;
        #pragma unroll
        for (int r2 = 0; r2 < 4; ++r2) {
            float x = accs[ct][r2] * invd[r2];
            float g = 0.5f * x * (1.0f + erff(x * 0.70710678118f)); // exact GELU
            out[(size_t)(i0 + q * 4 + r2) * NF + n] = g;
        }
    }
}

// ---------------------------------------------------------------------------
extern "C" void kernel_launch(void* const* d_in, const int* in_sizes, int n_in,
                              void* d_out, int out_size, void* d_ws, size_t ws_size,
                              hipStream_t stream) {
    const float* X = (const float*)d_in[0];   // fp32 8192x256
    const int*   A = (const int*)d_in[1];     // int32 8192x8192
    const float* W = (const float*)d_in[2];   // fp32 256x256
    const float* r = (const float*)d_in[3];   // fp32 512
    float* out = (float*)d_out;

    // ws: WhT bf16 (4MB) | sp_src (128KB) | sp_dst (128KB) | s_src | s_dst | pmax
    short* WhT    = (short*)d_ws;
    float* sp_src = (float*)((char*)d_ws + (size_t)NF * N_NODES * sizeof(short));
    float* sp_dst = sp_src + 4 * N_NODES;
    float* s_src  = sp_dst + 4 * N_NODES;
    float* s_dst  = s_src + N_NODES;
    float* pmax   = s_dst + N_NODES;

    k1_gemm<<<512, 256, 0, stream>>>(X, W, r, WhT, sp_src, sp_dst);
    k2_sv<<<32, 256, 0, stream>>>(sp_src, sp_dst, s_src, s_dst, pmax);
    k4_attn<<<256, 512, 0, stream>>>(A, WhT, s_dst, s_src, pmax, out);
}

// Round 4
// 521.052 us; speedup vs baseline: 1.3113x; 1.3113x over previous
//
#include <hip/hip_runtime.h>
#include <hip/hip_bf16.h>

#define N_NODES 8192
#define NF      256
#define L2E     1.44269504088896341f

typedef __attribute__((ext_vector_type(8))) short short8;
typedef __attribute__((ext_vector_type(4))) short short4v;
typedef __attribute__((ext_vector_type(4))) float floatx4;

static __device__ __forceinline__ float bf2f(short s) {
    return __uint_as_float(((unsigned)(unsigned short)s) << 16);
}
static __device__ __forceinline__ short f2bf_rn(float f) {
    unsigned u = __float_as_uint(f) + 0x8000u;
    return (short)(u >> 16);
}
struct bfpair { short hi, lo; };
static __device__ __forceinline__ bfpair split_bf(float x) {
    bfpair p;
    p.hi = f2bf_rn(x);
    p.lo = f2bf_rn(x - bf2f(p.hi));
    return p;
}

// async global->LDS, 16B per lane, dest = uniform base + lane*16
static __device__ __forceinline__ void async16(const void* g, void* l) {
    __builtin_amdgcn_global_load_lds(
        (const __attribute__((address_space(1))) unsigned*)g,
        (__attribute__((address_space(3))) unsigned*)l, 16, 0, 0);
}

// ---------------------------------------------------------------------------
// K1: WhT[n][i] = sum_k X[i][k] * W[n][k]  (fp32 via hi/lo bf16 MFMA, fp32 acc)
// + per-nb partials of s_src/s_dst. (unchanged from R3)
// ---------------------------------------------------------------------------
__global__ __launch_bounds__(256) void k1_gemm(const float* __restrict__ X,
                                               const float* __restrict__ W,
                                               const float* __restrict__ r,
                                               short* __restrict__ WhT,
                                               float* __restrict__ sp_src,
                                               float* __restrict__ sp_dst) {
    const int ib = blockIdx.x >> 2;
    const int nb = blockIdx.x & 3;
    const int wave = threadIdx.x >> 6, lane = threadIdx.x & 63;
    const int q = lane >> 4, m = lane & 15;
    const int irow = ib * 64 + wave * 16 + m;

    floatx4 acc[4] = {};
    const float* xp = X + (size_t)irow * NF;
    #pragma unroll
    for (int ks = 0; ks < 8; ++ks) {
        const float* xq = xp + ks * 32 + q * 8;
        float4 xa = *(const float4*)(xq);
        float4 xb = *(const float4*)(xq + 4);
        const float xs[8] = {xa.x, xa.y, xa.z, xa.w, xb.x, xb.y, xb.z, xb.w};
        short8 xh, xl;
        #pragma unroll
        for (int c = 0; c < 8; ++c) {
            bfpair p = split_bf(xs[c]);
            xh[c] = p.hi; xl[c] = p.lo;
        }
        #pragma unroll
        for (int ct = 0; ct < 4; ++ct) {
            const int n = nb * 64 + ct * 16 + m;
            const float* wp = W + (size_t)n * NF + ks * 32 + q * 8;
            float4 wa = *(const float4*)(wp);
            float4 wb = *(const float4*)(wp + 4);
            const float wsv[8] = {wa.x, wa.y, wa.z, wa.w, wb.x, wb.y, wb.z, wb.w};
            short8 wh, wl;
            #pragma unroll
            for (int c = 0; c < 8; ++c) {
                bfpair p = split_bf(wsv[c]);
                wh[c] = p.hi; wl[c] = p.lo;
            }
            acc[ct] = __builtin_amdgcn_mfma_f32_16x16x32_bf16(xh, wh, acc[ct], 0, 0, 0);
            acc[ct] = __builtin_amdgcn_mfma_f32_16x16x32_bf16(xh, wl, acc[ct], 0, 0, 0);
            acc[ct] = __builtin_amdgcn_mfma_f32_16x16x32_bf16(xl, wh, acc[ct], 0, 0, 0);
        }
    }

    const int i0 = ib * 64 + wave * 16 + q * 4;
    float vs[4] = {0.f, 0.f, 0.f, 0.f}, vd[4] = {0.f, 0.f, 0.f, 0.f};
    #pragma unroll
    for (int ct = 0; ct < 4; ++ct) {
        const int n = nb * 64 + ct * 16 + m;
        short4v v;
        #pragma unroll
        for (int r2 = 0; r2 < 4; ++r2) v[r2] = f2bf_rn(acc[ct][r2]);
        *(short4v*)(WhT + (size_t)n * N_NODES + i0) = v;
        const float rs = r[n], rd = r[NF + n];
        #pragma unroll
        for (int r2 = 0; r2 < 4; ++r2) {
            vs[r2] = fmaf(acc[ct][r2], rs, vs[r2]);
            vd[r2] = fmaf(acc[ct][r2], rd, vd[r2]);
        }
    }
    #pragma unroll
    for (int mask = 1; mask <= 8; mask <<= 1) {
        #pragma unroll
        for (int r2 = 0; r2 < 4; ++r2) {
            vs[r2] += __shfl_xor(vs[r2], mask);
            vd[r2] += __shfl_xor(vd[r2], mask);
        }
    }
    if (m == 0) {
        #pragma unroll
        for (int r2 = 0; r2 < 4; ++r2) {
            sp_src[nb * N_NODES + i0 + r2] = vs[r2];
            sp_dst[nb * N_NODES + i0 + r2] = vd[r2];
        }
    }
}

// ---------------------------------------------------------------------------
// K2: sum 4 n-block partials -> s_src/s_dst; per-block max(s_dst) -> pmax
// ---------------------------------------------------------------------------
__global__ __launch_bounds__(256) void k2_sv(const float* __restrict__ sp_src,
                                             const float* __restrict__ sp_dst,
                                             float* __restrict__ s_src,
                                             float* __restrict__ s_dst,
                                             float* __restrict__ pmax) {
    __shared__ float red[256];
    const int tid = threadIdx.x;
    const int i = blockIdx.x * 256 + tid;
    float ss = 0.f, sd = 0.f;
    #pragma unroll
    for (int nb = 0; nb < 4; ++nb) {
        ss += sp_src[nb * N_NODES + i];
        sd += sp_dst[nb * N_NODES + i];
    }
    s_src[i] = ss;
    s_dst[i] = sd;
    red[tid] = sd;
    __syncthreads();
    for (int off = 128; off > 0; off >>= 1) {
        if (tid < off) red[tid] = fmaxf(red[tid], red[tid + off]);
        __syncthreads();
    }
    if (tid == 0) pmax[blockIdx.x] = red[0];
}

// ---------------------------------------------------------------------------
// K4: fused masked-softmax attention + PV MFMA + exact GELU.
// 256 blocks x 512 thr (8 waves). Block owns 32 rows, sweeps j in 64-tiles.
// A-tile (8KB) + B-tile (32KB) staged to LDS once per block-iter via
// global_load_lds (async, 16B), double-buffered, XOR-swizzled chunk layout.
// ---------------------------------------------------------------------------
static __device__ __forceinline__ void pgroup(const int4 a, const floatx4 t,
                                              const float s_i, const float d_i,
                                              float* p) {
    const int av[4] = {a.x, a.y, a.z, a.w};
    #pragma unroll
    for (int c = 0; c < 4; ++c) {
        float sum = s_i + t[c];
        float lr  = fmaxf(sum, 0.2f * sum);
        float pp  = __builtin_amdgcn_exp2f(fmaf(lr, L2E, d_i));
        p[c] = (av[c] != 0) ? pp : 0.0f;
    }
}

__global__ __launch_bounds__(512, 2) void k4_attn(const int* __restrict__ Adj,
                                                  const short* __restrict__ WhT,
                                                  const float* __restrict__ s_dst,
                                                  const float* __restrict__ s_src,
                                                  const float* __restrict__ pmax,
                                                  float* __restrict__ out) {
    // LDS: double-buffered B (64j x 256n bf16, rows of 64 shorts, 16B-chunk
    // slot = chunk ^ (n&7)) and A (64j x 32r int, rows of 64 ints, 16B-chunk
    // slot = chunk ^ ((r&7)*2)).
    __shared__ short Bbuf[2][256 * 64];
    __shared__ int   Abuf[2][32 * 64];

    const int tid = threadIdx.x;
    const int wave = tid >> 6, lane = tid & 63;
    const int q = lane >> 4, m = lane & 15;
    const int rowhalf = wave & 1, cg = wave >> 1;
    const int i0 = blockIdx.x * 32;
    const int row = i0 + rowhalf * 16 + m;
    const int n0 = cg * 64;

    float M = pmax[0];
    #pragma unroll
    for (int b = 1; b < 32; ++b) M = fmaxf(M, pmax[b]);
    const float s_i = s_src[row];
    const float e0 = s_i + M;
    const float d_i = -fmaxf(e0, 0.2f * e0) * L2E;

    // ---- staging constants (per lane) ----
    const int rB = lane >> 3;                 // 0..7 (row within 8-row group)
    const int cB = (lane & 7) ^ rB;           // global 16B-chunk fetched
    const int rA = lane >> 4;                 // 0..3
    const int rlocA = wave * 4 + rA;          // A row 0..31
    const int kA = (lane & 15) ^ ((rlocA & 7) * 2);
    const short* gB[4];
    #pragma unroll
    for (int u = 0; u < 4; ++u)
        gB[u] = WhT + (size_t)((wave * 4 + u) * 8 + rB) * N_NODES + cB * 8;
    const int* gA = Adj + (size_t)(i0 + rlocA) * N_NODES + kA * 4;

    // ---- read offsets (per lane, constant across iters) ----
    const int r_l = rowhalf * 16 + m;
    const int swA = (r_l & 7) * 2;
    const int aoff0 = r_l * 64 + (((2 * q)     ^ swA) * 4);
    const int aoff1 = r_l * 64 + (((2 * q + 1) ^ swA) * 4);
    const int aoff2 = r_l * 64 + (((2 * q + 8) ^ swA) * 4);
    const int aoff3 = r_l * 64 + (((2 * q + 9) ^ swA) * 4);
    int boff0[4], boff1[4];
    #pragma unroll
    for (int ct = 0; ct < 4; ++ct) {
        const int n_l = n0 + ct * 16 + m;
        const int sw = n_l & 7;
        boff0[ct] = n_l * 64 + ((q ^ sw) * 8);
        boff1[ct] = n_l * 64 + ((((q + 4) ^ sw)) * 8);
    }

    floatx4 acc0 = {}, acc1 = {}, acc2 = {}, acc3 = {};
    float den = 0.f;

    // ---- stage tile 0 into buf 0 ----
    #pragma unroll
    for (int u = 0; u < 4; ++u)
        async16(gB[u], &Bbuf[0][(wave * 4 + u) * 512]);
    async16(gA, &Abuf[0][wave * 256]);

    // t-prefetch (global, L2-hot broadcast lines) for tile 0
    const int jq = q * 8;
    floatx4 t0 = *(const floatx4*)(s_dst + jq);
    floatx4 t1 = *(const floatx4*)(s_dst + jq + 4);
    floatx4 t2 = *(const floatx4*)(s_dst + jq + 32);
    floatx4 t3 = *(const floatx4*)(s_dst + jq + 36);

    __syncthreads();

    for (int jt = 0; jt < 128; ++jt) {
        const int buf = jt & 1;
        const short* Bc = Bbuf[buf];
        const int*   Ac = Abuf[buf];

        // stage next tile (async; drained by the barrier at loop end)
        if (jt < 127) {
            const int jbn = (jt + 1) * 64;
            #pragma unroll
            for (int u = 0; u < 4; ++u)
                async16(gB[u] + jbn, &Bbuf[buf ^ 1][(wave * 4 + u) * 512]);
            async16(gA + jbn, &Abuf[buf ^ 1][wave * 256]);
        }

        // t for next tile
        const int jn = (jt < 127) ? (jt + 1) * 64 : jt * 64;
        floatx4 nt0 = *(const floatx4*)(s_dst + jn + jq);
        floatx4 nt1 = *(const floatx4*)(s_dst + jn + jq + 4);
        floatx4 nt2 = *(const floatx4*)(s_dst + jn + jq + 32);
        floatx4 nt3 = *(const floatx4*)(s_dst + jn + jq + 36);

        // fragments from LDS
        short8 b00 = *(const short8*)(Bc + boff0[0]);
        short8 b01 = *(const short8*)(Bc + boff1[0]);
        short8 b10 = *(const short8*)(Bc + boff0[1]);
        short8 b11 = *(const short8*)(Bc + boff1[1]);
        short8 b20 = *(const short8*)(Bc + boff0[2]);
        short8 b21 = *(const short8*)(Bc + boff1[2]);
        short8 b30 = *(const short8*)(Bc + boff0[3]);
        short8 b31 = *(const short8*)(Bc + boff1[3]);
        int4 a0 = *(const int4*)(Ac + aoff0);
        int4 a1 = *(const int4*)(Ac + aoff1);
        int4 a2 = *(const int4*)(Ac + aoff2);
        int4 a3 = *(const int4*)(Ac + aoff3);

        float p[16];
        pgroup(a0, t0, s_i, d_i, p);
        pgroup(a1, t1, s_i, d_i, p + 4);
        pgroup(a2, t2, s_i, d_i, p + 8);
        pgroup(a3, t3, s_i, d_i, p + 12);

        short8 af0, af1;
        #pragma unroll
        for (int c = 0; c < 8; ++c) { af0[c] = f2bf_rn(p[c]); af1[c] = f2bf_rn(p[8 + c]); }
        float ds = 0.f;
        #pragma unroll
        for (int c = 0; c < 16; ++c) ds += p[c];
        den += ds;

        acc0 = __builtin_amdgcn_mfma_f32_16x16x32_bf16(af0, b00, acc0, 0, 0, 0);
        acc0 = __builtin_amdgcn_mfma_f32_16x16x32_bf16(af1, b01, acc0, 0, 0, 0);
        acc1 = __builtin_amdgcn_mfma_f32_16x16x32_bf16(af0, b10, acc1, 0, 0, 0);
        acc1 = __builtin_amdgcn_mfma_f32_16x16x32_bf16(af1, b11, acc1, 0, 0, 0);
        acc2 = __builtin_amdgcn_mfma_f32_16x16x32_bf16(af0, b20, acc2, 0, 0, 0);
        acc2 = __builtin_amdgcn_mfma_f32_16x16x32_bf16(af1, b21, acc2, 0, 0, 0);
        acc3 = __builtin_amdgcn_mfma_f32_16x16x32_bf16(af0, b30, acc3, 0, 0, 0);
        acc3 = __builtin_amdgcn_mfma_f32_16x16x32_bf16(af1, b31, acc3, 0, 0, 0);

        t0 = nt0; t1 = nt1; t2 = nt2; t3 = nt3;

        __syncthreads();   // drains staging (vmcnt) + protects buf reuse
    }

    den += __shfl_xor(den, 16);
    den += __shfl_xor(den, 32);
    float invd[4];
    #pragma unroll
    for (int r2 = 0; r2 < 4; ++r2)
        invd[r2] = 1.0f / fmaxf(__shfl(den, q * 4 + r2), 1e-30f);

    const int io = i0 + rowhalf * 16;
    floatx4 accs[4] = {acc0, acc1, acc2, acc3};
    #pragma unroll
    for (int ct = 0; ct < 4; ++ct) {
        const int n = n0 + ct * 16 + m;
        #pragma unroll
        for (int r2 = 0; r2 < 4; ++r2) {
            float x = accs[ct][r2] * invd[r2];
            float g = 0.5f * x * (1.0f + erff(x * 0.70710678118f));
            out[(size_t)(io + q * 4 + r2) * NF + n] = g;
        }
    }
}

// ---------------------------------------------------------------------------
extern "C" void kernel_launch(void* const* d_in, const int* in_sizes, int n_in,
                              void* d_out, int out_size, void* d_ws, size_t ws_size,
                              hipStream_t stream) {
    const float* X = (const float*)d_in[0];   // fp32 8192x256
    const int*   A = (const int*)d_in[1];     // int32 8192x8192
    const float* W = (const float*)d_in[2];   // fp32 256x256
    const float* r = (const float*)d_in[3];   // fp32 512
    float* out = (float*)d_out;

    short* WhT    = (short*)d_ws;
    float* sp_src = (float*)((char*)d_ws + (size_t)NF * N_NODES * sizeof(short));
    float* sp_dst = sp_src + 4 * N_NODES;
    float* s_src  = sp_dst + 4 * N_NODES;
    float* s_dst  = s_src + N_NODES;
    float* pmax   = s_dst + N_NODES;

    k1_gemm<<<512, 256, 0, stream>>>(X, W, r, WhT, sp_src, sp_dst);
    k2_sv<<<32, 256, 0, stream>>>(sp_src, sp_dst, s_src, s_dst, pmax);
    k4_attn<<<256, 512, 0, stream>>>(A, WhT, s_dst, s_src, pmax, out);
}

// Round 5
// 481.700 us; speedup vs baseline: 1.4184x; 1.0817x over previous
//
#include <hip/hip_runtime.h>
#include <hip/hip_bf16.h>

#define N_NODES 8192
#define NF      256
#define L2E     1.44269504088896341f

typedef __attribute__((ext_vector_type(8))) short short8;
typedef __attribute__((ext_vector_type(4))) short short4v;
typedef __attribute__((ext_vector_type(4))) float floatx4;

static __device__ __forceinline__ float bf2f(short s) {
    return __uint_as_float(((unsigned)(unsigned short)s) << 16);
}
static __device__ __forceinline__ short f2bf_rn(float f) {
    unsigned u = __float_as_uint(f) + 0x8000u;
    return (short)(u >> 16);
}
struct bfpair { short hi, lo; };
static __device__ __forceinline__ bfpair split_bf(float x) {
    bfpair p;
    p.hi = f2bf_rn(x);
    p.lo = f2bf_rn(x - bf2f(p.hi));
    return p;
}
// async global->LDS, 16B/lane, LDS dest = uniform base + lane*16
static __device__ __forceinline__ void async16(const void* g, void* l) {
    __builtin_amdgcn_global_load_lds(
        (const __attribute__((address_space(1))) unsigned*)g,
        (__attribute__((address_space(3))) unsigned*)l, 16, 0, 0);
}

// ---------------------------------------------------------------------------
// KX: split W (256x256 fp32) into bf16 hi/lo arrays, once.
// ---------------------------------------------------------------------------
__global__ __launch_bounds__(256) void kx_split(const float* __restrict__ W,
                                                short* __restrict__ Whi,
                                                short* __restrict__ Wlo) {
    #pragma unroll
    for (int e = 0; e < 4; ++e) {
        const int i = blockIdx.x * 1024 + e * 256 + threadIdx.x;
        bfpair p = split_bf(W[i]);
        Whi[i] = p.hi;
        Wlo[i] = p.lo;
    }
}

// ---------------------------------------------------------------------------
// K1: WhT[n][i] = sum_k X[i][k]*W[n][k] via hi/lo bf16 MFMA (fp32-accurate).
// Also emits per-cq partials of s_src/s_dst from fp32 accumulators.
// grid 256 (32 i-rows each) x 512 thr (8 waves = 2 rowhalf x 4 colquarter).
// X staged fp32 -> LDS (async16, 16B-chunk XOR swizzle), split in-register.
// ---------------------------------------------------------------------------
__global__ __launch_bounds__(512) void k1_gemm(const float* __restrict__ X,
                                               const short* __restrict__ Whi,
                                               const short* __restrict__ Wlo,
                                               const float* __restrict__ r,
                                               short* __restrict__ WhT,
                                               float* __restrict__ sp_src,
                                               float* __restrict__ sp_dst) {
    __shared__ float Xs[32 * 256];   // 32 KB; chunk slot = c ^ (row&7)

    const int tid = threadIdx.x;
    const int w = tid >> 6, lane = tid & 63;
    const int q = lane >> 4, m = lane & 15;
    const int rh = w >> 2, cq = w & 3;
    const int i_base = blockIdx.x * 32;

    // stage 32 rows of X (1 KB each); 4 instrs/wave
    #pragma unroll
    for (int v = 0; v < 4; ++v) {
        const int rowv = w * 4 + v;
        const int c = lane ^ (rowv & 7);
        async16(X + (size_t)(i_base + rowv) * NF + c * 4, &Xs[rowv * 256]);
    }
    __syncthreads();

    floatx4 acc[4] = {};
    const int xrow = rh * 16 + m;
    const int r7 = xrow & 7;
    #pragma unroll
    for (int ks = 0; ks < 8; ++ks) {
        const int c0 = ks * 8 + q * 2;
        float4 f0 = *(const float4*)(&Xs[xrow * 256 + ((c0 ^ r7) * 4)]);
        float4 f1 = *(const float4*)(&Xs[xrow * 256 + (((c0 + 1) ^ r7) * 4)]);
        const float xsv[8] = {f0.x, f0.y, f0.z, f0.w, f1.x, f1.y, f1.z, f1.w};
        short8 xh, xl;
        #pragma unroll
        for (int c = 0; c < 8; ++c) {
            bfpair p = split_bf(xsv[c]);
            xh[c] = p.hi; xl[c] = p.lo;
        }
        #pragma unroll
        for (int nt = 0; nt < 4; ++nt) {
            const int n = cq * 64 + nt * 16 + m;
            short8 wh = *(const short8*)(Whi + n * NF + ks * 32 + q * 8);
            short8 wl = *(const short8*)(Wlo + n * NF + ks * 32 + q * 8);
            acc[nt] = __builtin_amdgcn_mfma_f32_16x16x32_bf16(xh, wh, acc[nt], 0, 0, 0);
            acc[nt] = __builtin_amdgcn_mfma_f32_16x16x32_bf16(xl, wh, acc[nt], 0, 0, 0);
            acc[nt] = __builtin_amdgcn_mfma_f32_16x16x32_bf16(xh, wl, acc[nt], 0, 0, 0);
        }
    }

    // C/D layout: col = lane&15 (n), row = q*4 + reg (i)
    const int i0 = i_base + rh * 16 + q * 4;
    float vs[4] = {0.f, 0.f, 0.f, 0.f}, vd[4] = {0.f, 0.f, 0.f, 0.f};
    #pragma unroll
    for (int nt = 0; nt < 4; ++nt) {
        const int n = cq * 64 + nt * 16 + m;
        short4v v;
        #pragma unroll
        for (int r2 = 0; r2 < 4; ++r2) v[r2] = f2bf_rn(acc[nt][r2]);
        *(short4v*)(WhT + (size_t)n * N_NODES + i0) = v;
        const float rs = r[n], rd = r[NF + n];
        #pragma unroll
        for (int r2 = 0; r2 < 4; ++r2) {
            vs[r2] = fmaf(acc[nt][r2], rs, vs[r2]);
            vd[r2] = fmaf(acc[nt][r2], rd, vd[r2]);
        }
    }
    #pragma unroll
    for (int mask = 1; mask <= 8; mask <<= 1) {
        #pragma unroll
        for (int r2 = 0; r2 < 4; ++r2) {
            vs[r2] += __shfl_xor(vs[r2], mask);
            vd[r2] += __shfl_xor(vd[r2], mask);
        }
    }
    if (m == 0) {
        #pragma unroll
        for (int r2 = 0; r2 < 4; ++r2) {
            sp_src[cq * N_NODES + i0 + r2] = vs[r2];
            sp_dst[cq * N_NODES + i0 + r2] = vd[r2];
        }
    }
}

// ---------------------------------------------------------------------------
// K2: sum 4 partials -> s_src/s_dst; per-block max(s_dst) -> pmax[32]
// ---------------------------------------------------------------------------
__global__ __launch_bounds__(256) void k2_sv(const float* __restrict__ sp_src,
                                             const float* __restrict__ sp_dst,
                                             float* __restrict__ s_src,
                                             float* __restrict__ s_dst,
                                             float* __restrict__ pmax) {
    __shared__ float red[256];
    const int tid = threadIdx.x;
    const int i = blockIdx.x * 256 + tid;
    float ss = 0.f, sd = 0.f;
    #pragma unroll
    for (int nb = 0; nb < 4; ++nb) {
        ss += sp_src[nb * N_NODES + i];
        sd += sp_dst[nb * N_NODES + i];
    }
    s_src[i] = ss;
    s_dst[i] = sd;
    red[tid] = sd;
    __syncthreads();
    for (int off = 128; off > 0; off >>= 1) {
        if (tid < off) red[tid] = fmaxf(red[tid], red[tid + off]);
        __syncthreads();
    }
    if (tid == 0) pmax[blockIdx.x] = red[0];
}

// ---------------------------------------------------------------------------
// K4: fused masked-softmax attention + PV MFMA + exact GELU.
// grid 256 x 1024 thr (16 waves = 2 rowhalf x 2 colhalf x 4 jquarter).
// No P duplication across colgroups beyond x2; A read by exactly one wave.
// B macro-tile (256j x 256n bf16 = 128 KB) single-buffered in LDS;
// A direct global->reg with one-macro prefetch. 2 barriers / 256 j.
// ---------------------------------------------------------------------------
static __device__ __forceinline__ void pgroup(const int4 a, const floatx4 t,
                                              const float s_i, const float d_i,
                                              float* p) {
    const int av[4] = {a.x, a.y, a.z, a.w};
    #pragma unroll
    for (int c = 0; c < 4; ++c) {
        float sum = s_i + t[c];
        float lr  = fmaxf(sum, 0.2f * sum);
        float pp  = __builtin_amdgcn_exp2f(fmaf(lr, L2E, d_i));
        p[c] = (av[c] != 0) ? pp : 0.0f;
    }
}

__global__ __launch_bounds__(1024) void k4_attn(const int* __restrict__ Adj,
                                                const short* __restrict__ WhT,
                                                const float* __restrict__ s_dst,
                                                const float* __restrict__ s_src,
                                                const float* __restrict__ pmax,
                                                float* __restrict__ out) {
    __shared__ union {
        short B[4 * 256 * 64];        // [jq][n][64 j-shorts], chunk slot = c^(n&7)
        float red[16 * 8 * 4 * 64];   // [wave][nt][reg][lane]
    } sm;
    __shared__ float denred[128];

    const int tid = threadIdx.x;
    const int w = tid >> 6, lane = tid & 63;
    const int q = lane >> 4, m = lane & 15;
    const int rh = w >> 3, ch = (w >> 2) & 1, jq = w & 3;
    const int i0 = blockIdx.x * 32;
    const int row = i0 + rh * 16 + m;

    float M = pmax[0];
    #pragma unroll
    for (int b = 1; b < 32; ++b) M = fmaxf(M, pmax[b]);
    const float s_i = s_src[row];
    const float e0 = s_i + M;
    const float d_i = -fmaxf(e0, 0.2f * e0) * L2E;   // -c_i*log2e, c_i >= row max

    // ---- B staging: wave (ug = w>>2, jqs = w&3) stages 8 KB x 8 instrs ----
    const int ug = w >> 2;
    const int jqs = w & 3;
    const int srow = lane >> 3;                  // n within 8-row group
    const int schunk = (lane & 7) ^ srow;        // global 16B chunk (swizzle)
    const short* gB = WhT + (size_t)(ug * 64 + srow) * N_NODES + jqs * 64 + schunk * 8;
    short* ldsB = sm.B + (jqs * 256 + ug * 64) * 64;

    // ---- A / t pointers (per lane) ----
    const int* Arow = Adj + (size_t)row * N_NODES + jq * 64 + q * 8;
    const float* tb = s_dst + jq * 64 + q * 8;

    floatx4 acc[8] = {{0.f,0.f,0.f,0.f}};
    #pragma unroll
    for (int nt = 0; nt < 8; ++nt) acc[nt] = (floatx4){0.f,0.f,0.f,0.f};
    float den = 0.f;

    // prologue: stage macro 0, prefetch A(0)
    #pragma unroll
    for (int v = 0; v < 8; ++v)
        async16(gB + v * 8 * N_NODES, ldsB + v * 8 * 64);
    int4 a0 = *(const int4*)(Arow);
    int4 a1 = *(const int4*)(Arow + 4);
    int4 a2 = *(const int4*)(Arow + 32);
    int4 a3 = *(const int4*)(Arow + 36);
    __syncthreads();

    for (int s = 0; s < 32; ++s) {
        // prefetch next macro's A (HBM, ~900cyc) into registers
        const int offn = (s < 31) ? (s + 1) * 256 : s * 256;
        int4 na0 = *(const int4*)(Arow + offn);
        int4 na1 = *(const int4*)(Arow + offn + 4);
        int4 na2 = *(const int4*)(Arow + offn + 32);
        int4 na3 = *(const int4*)(Arow + offn + 36);
        // t for this macro (L2-hot broadcast)
        const int ts = s * 256;
        floatx4 t0 = *(const floatx4*)(tb + ts);
        floatx4 t1 = *(const floatx4*)(tb + ts + 4);
        floatx4 t2 = *(const floatx4*)(tb + ts + 32);
        floatx4 t3 = *(const floatx4*)(tb + ts + 36);

        float p[16];
        pgroup(a0, t0, s_i, d_i, p);
        pgroup(a1, t1, s_i, d_i, p + 4);
        pgroup(a2, t2, s_i, d_i, p + 8);
        pgroup(a3, t3, s_i, d_i, p + 12);

        short8 af0, af1;
        #pragma unroll
        for (int c = 0; c < 8; ++c) { af0[c] = f2bf_rn(p[c]); af1[c] = f2bf_rn(p[8 + c]); }
        float ds = 0.f;
        #pragma unroll
        for (int c = 0; c < 16; ++c) ds += p[c];
        den += ds;

        const short* Bj = sm.B + jq * 256 * 64;
        #pragma unroll
        for (int nt = 0; nt < 8; ++nt) {
            const int n = ch * 128 + nt * 16 + m;
            const short* bp = Bj + n * 64;
            const int sw = n & 7;
            short8 b0 = *(const short8*)(bp + ((q ^ sw) * 8));
            short8 b1 = *(const short8*)(bp + (((q + 4) ^ sw) * 8));
            acc[nt] = __builtin_amdgcn_mfma_f32_16x16x32_bf16(af0, b0, acc[nt], 0, 0, 0);
            acc[nt] = __builtin_amdgcn_mfma_f32_16x16x32_bf16(af1, b1, acc[nt], 0, 0, 0);
        }
        a0 = na0; a1 = na1; a2 = na2; a3 = na3;

        __syncthreads();                 // all Bbuf reads done
        if (s < 31) {
            const int go = (s + 1) * 256;
            #pragma unroll
            for (int v = 0; v < 8; ++v)
                async16(gB + go + v * 8 * N_NODES, ldsB + v * 8 * 64);
            __syncthreads();             // staging landed (vmcnt drained)
        }
    }

    // ---- epilogue: reduce den and acc across the 4 jq waves ----
    den += __shfl_xor(den, 16);
    den += __shfl_xor(den, 32);
    if (ch == 0 && lane < 16) denred[rh * 64 + jq * 16 + lane] = den;
    #pragma unroll
    for (int nt = 0; nt < 8; ++nt)
        #pragma unroll
        for (int rg = 0; rg < 4; ++rg)
            sm.red[((w * 8 + nt) * 4 + rg) * 64 + lane] = acc[nt][rg];
    __syncthreads();

    float invd[4];
    #pragma unroll
    for (int rg = 0; rg < 4; ++rg) {
        const int rr = rh * 64 + q * 4 + rg;
        invd[rg] = 1.0f / fmaxf(denred[rr] + denred[rr + 16] +
                                denred[rr + 32] + denred[rr + 48], 1e-30f);
    }
    const int wb = rh * 8 + ch * 4;
    #pragma unroll
    for (int t2 = 0; t2 < 2; ++t2) {
        const int nt = jq * 2 + t2;
        #pragma unroll
        for (int rg = 0; rg < 4; ++rg) {
            float v = sm.red[(((wb + 0) * 8 + nt) * 4 + rg) * 64 + lane]
                    + sm.red[(((wb + 1) * 8 + nt) * 4 + rg) * 64 + lane]
                    + sm.red[(((wb + 2) * 8 + nt) * 4 + rg) * 64 + lane]
                    + sm.red[(((wb + 3) * 8 + nt) * 4 + rg) * 64 + lane];
            float x = v * invd[rg];
            float g = 0.5f * x * (1.0f + erff(x * 0.70710678118f)); // exact GELU
            out[(size_t)(i0 + rh * 16 + q * 4 + rg) * NF + ch * 128 + nt * 16 + m] = g;
        }
    }
}

// ---------------------------------------------------------------------------
extern "C" void kernel_launch(void* const* d_in, const int* in_sizes, int n_in,
                              void* d_out, int out_size, void* d_ws, size_t ws_size,
                              hipStream_t stream) {
    const float* X = (const float*)d_in[0];   // fp32 8192x256
    const int*   A = (const int*)d_in[1];     // int32 8192x8192
    const float* W = (const float*)d_in[2];   // fp32 256x256
    const float* r = (const float*)d_in[3];   // fp32 512
    float* out = (float*)d_out;

    // ws: WhT bf16 4MB | Whi 128K | Wlo 128K | sp_src 128K | sp_dst 128K |
    //     s_src 32K | s_dst 32K | pmax 128B
    char* wsp = (char*)d_ws;
    short* WhT    = (short*)wsp;                    wsp += (size_t)NF * N_NODES * 2;
    short* Whi    = (short*)wsp;                    wsp += NF * NF * 2;
    short* Wlo    = (short*)wsp;                    wsp += NF * NF * 2;
    float* sp_src = (float*)wsp;                    wsp += 4 * N_NODES * 4;
    float* sp_dst = (float*)wsp;                    wsp += 4 * N_NODES * 4;
    float* s_src  = (float*)wsp;                    wsp += N_NODES * 4;
    float* s_dst  = (float*)wsp;                    wsp += N_NODES * 4;
    float* pmax   = (float*)wsp;

    kx_split<<<64, 256, 0, stream>>>(W, Whi, Wlo);
    k1_gemm<<<256, 512, 0, stream>>>(X, Whi, Wlo, r, WhT, sp_src, sp_dst);
    k2_sv<<<32, 256, 0, stream>>>(sp_src, sp_dst, s_src, s_dst, pmax);
    k4_attn<<<256, 1024, 0, stream>>>(A, WhT, s_dst, s_src, pmax, out);
}